// Round 2
// 3811.469 us; speedup vs baseline: 2.9008x; 2.9008x over previous
//
#include <hip/hip_runtime.h>
#include <hip/hip_bf16.h>

#define DXc 256
#define DYc 32
#define Kc 4
#define Hc 128
#define LRf 0.1f
#define REGf 0.01f
#define TSTEPS 1000

typedef __attribute__((ext_vector_type(8))) short s8b;    // 8 x bf16 (4 VGPRs)
typedef __attribute__((ext_vector_type(4))) float f32x4;  // MFMA accumulator

#define MFMA16(a, b, c) __builtin_amdgcn_mfma_f32_16x16x32_bf16((a), (b), (c), 0, 0, 0)

// 6-product "f32-exact" MFMA: A=a0+a1+a2, B=b0+b1+b2 (exact 3-way bf16 splits),
// keep terms down to 2^-18 order; dropped terms ~2^-24 relative.
#define MFMA6(A0, A1, A2, B0, B1, B2, acc)      \
    do {                                        \
        acc = MFMA16((A0), (B0), acc);          \
        acc = MFMA16((A0), (B1), acc);          \
        acc = MFMA16((A1), (B0), acc);          \
        acc = MFMA16((A0), (B2), acc);          \
        acc = MFMA16((A1), (B1), acc);          \
        acc = MFMA16((A2), (B0), acc);          \
    } while (0)

// ---- bf16 split helpers ----
__device__ __forceinline__ float hipart(float a) {
    return __uint_as_float(__float_as_uint(a) & 0xffff0000u);
}
__device__ __forceinline__ unsigned hi2(float a, float b) {
    return (__float_as_uint(a) >> 16) | (__float_as_uint(b) & 0xffff0000u);
}
// 2-way truncation split (residual ~2^-16 rel) — backward/smooth paths
__device__ __forceinline__ void wsplit(float x, unsigned short* __restrict__ h,
                                       unsigned short* __restrict__ l) {
    unsigned u = __float_as_uint(x);
    *h = (unsigned short)(u >> 16);
    float hf = __uint_as_float(u & 0xffff0000u);
    *l = (unsigned short)(__float_as_uint(x - hf) >> 16);
}
// 3-way truncation split — EXACT (8+8+8 >= 24 mantissa bits)
__device__ __forceinline__ void wsplit3(float x, unsigned short* __restrict__ p0,
                                        unsigned short* __restrict__ p1,
                                        unsigned short* __restrict__ p2) {
    unsigned u = __float_as_uint(x);
    *p0 = (unsigned short)(u >> 16);
    float r1 = x - __uint_as_float(u & 0xffff0000u);
    unsigned u1 = __float_as_uint(r1);
    *p1 = (unsigned short)(u1 >> 16);
    float r2 = r1 - __uint_as_float(u1 & 0xffff0000u);
    *p2 = (unsigned short)(__float_as_uint(r2) >> 16);
}
// exact 3-way split of 8 packed floats into 3 bf16x8 fragments
__device__ __forceinline__ void split3x8(const float* v, s8b& A0, s8b& A1, s8b& A2) {
    union { s8b s; unsigned u[4]; } P0, P1, P2;
    #pragma unroll
    for (int m = 0; m < 4; ++m) {
        float a = v[2 * m], b = v[2 * m + 1];
        unsigned ua = __float_as_uint(a), ub = __float_as_uint(b);
        P0.u[m] = (ua >> 16) | (ub & 0xffff0000u);
        float ra = a - __uint_as_float(ua & 0xffff0000u);
        float rb = b - __uint_as_float(ub & 0xffff0000u);
        unsigned ura = __float_as_uint(ra), urb = __float_as_uint(rb);
        P1.u[m] = (ura >> 16) | (urb & 0xffff0000u);
        float ra2 = ra - __uint_as_float(ura & 0xffff0000u);
        float rb2 = rb - __uint_as_float(urb & 0xffff0000u);
        P2.u[m] = (__float_as_uint(ra2) >> 16) | (__float_as_uint(rb2) & 0xffff0000u);
    }
    A0 = P0.s; A1 = P1.s; A2 = P2.s;
}

// ---------------------------------------------------------------------------
// Setup kernel: derived weight matrices into workspace.
//   Wcat (256x256) = [ e_w1[:256] | P ]  where P = s_xw @ A0,  A0 = tr1w[0:128]
//   W1   (32x256)  = [ Wy | M ]          Wy = e_w1[256:288], M = s_yw @ A1
//   d0   (4x128)   = temb[t]@A2 + th[t]@A3 + s_yb@A1 + s_xb@A0 + tr1b
// bf16 split arrays (k-contiguous "B^T" layouts for MFMA B-frags):
//   W1Tb0/1/2 [256][32] : exact 3-plane of W1^T      (P1 forward, hi-prec)
//   ew2Tb0/1/2[128][128]: exact 3-plane of e_w2^T    (P3 forward, hi-prec)
//   ew2b h/l  [128][128]: 2-plane of e_w2 row-major  (P4 backward)
//   Wdy  h/l  [32][256] : 2-plane of [ M | Wy ]      (P5 backward)
// ---------------------------------------------------------------------------
__global__ __launch_bounds__(256) void setup_kernel(
    const float* __restrict__ e_w1, const float* __restrict__ s_xw,
    const float* __restrict__ s_yw, const float* __restrict__ s_temb,
    const float* __restrict__ s_t1w, const float* __restrict__ s_t1b,
    const float* __restrict__ s_t2w, const float* __restrict__ s_t2b,
    const float* __restrict__ tr1w, const float* __restrict__ tr1b,
    const float* __restrict__ s_xb, const float* __restrict__ s_yb,
    const float* __restrict__ e_w2,
    float* __restrict__ Wcat, float* __restrict__ W1, float* __restrict__ d0,
    unsigned short* __restrict__ W1Tb0, unsigned short* __restrict__ W1Tb1,
    unsigned short* __restrict__ W1Tb2,
    unsigned short* __restrict__ ew2Tb0, unsigned short* __restrict__ ew2Tb1,
    unsigned short* __restrict__ ew2Tb2,
    unsigned short* __restrict__ ew2bh, unsigned short* __restrict__ ew2bl,
    unsigned short* __restrict__ Wdybh, unsigned short* __restrict__ Wdybl)
{
    const int b = blockIdx.x;
    const int t = threadIdx.x;
    if (b < 64) {
        #pragma unroll
        for (int i = 0; i < 2; ++i) {
            int idx = t + 256 * i;              // 0..511
            int k = 4 * b + (idx >> 7);
            int c = idx & 127;
            float acc = 0.f;
            for (int h = 0; h < 128; ++h)
                acc += s_xw[k * 128 + h] * tr1w[h * 128 + c];
            Wcat[k * 256 + 128 + c] = acc;
            Wcat[k * 256 + c] = e_w1[k * 128 + c];
        }
    } else if (b == 64) {
        // M = s_yw @ A1   (W1 cols 128..255)
        #pragma unroll
        for (int i = 0; i < 16; ++i) {
            int idx = t + 256 * i;              // 0..4095
            int d = idx >> 7, c = idx & 127;
            float acc = 0.f;
            for (int h = 0; h < 128; ++h)
                acc += s_yw[d * 128 + h] * tr1w[(128 + h) * 128 + c];
            W1[d * 256 + 128 + c] = acc;
            wsplit3(acc, &W1Tb0[(128 + c) * 32 + d], &W1Tb1[(128 + c) * 32 + d],
                    &W1Tb2[(128 + c) * 32 + d]);
            wsplit(acc, &Wdybh[d * 256 + c], &Wdybl[d * 256 + c]);
        }
    } else if (b == 65) {
        // Wy = e_w1[256:288]  (W1 cols 0..127)
        #pragma unroll
        for (int i = 0; i < 16; ++i) {
            int idx = t + 256 * i;
            int d = idx >> 7, c = idx & 127;
            float v = e_w1[(DXc + d) * 128 + c];
            W1[d * 256 + c] = v;
            wsplit3(v, &W1Tb0[c * 32 + d], &W1Tb1[c * 32 + d], &W1Tb2[c * 32 + d]);
            wsplit(v, &Wdybh[d * 256 + 128 + c], &Wdybl[d * 256 + 128 + c]);
        }
    } else if (b == 66) {
        // e_w2 splits (both orientations)
        #pragma unroll
        for (int i = 0; i < 64; ++i) {
            int idx = t + 256 * i;
            int h = idx >> 7, c = idx & 127;
            float v = e_w2[h * 128 + c];
            wsplit3(v, &ew2Tb0[c * 128 + h], &ew2Tb1[c * 128 + h],
                    &ew2Tb2[c * 128 + h]);
            wsplit(v, &ew2bh[h * 128 + c], &ew2bl[h * 128 + c]);
        }
    } else {
        // b == 67: th table then d0 table
        __shared__ float thS[4][128];
        #pragma unroll
        for (int i = 0; i < 2; ++i) {
            int idx = t + 256 * i;              // 0..511
            int tt = idx >> 7, c = idx & 127;
            float tau = (float)tt / (float)TSTEPS;
            if (tau < 1e-6f) tau = 1e-6f;
            float acc = s_t2b[c];
            for (int h = 0; h < 128; ++h) {
                float aa = tau * s_t1w[h] + s_t1b[h];
                float s = 1.f / (1.f + expf(-aa));
                acc += aa * s * s_t2w[h * 128 + c];
            }
            thS[tt][c] = acc;
        }
        __syncthreads();
        #pragma unroll
        for (int i = 0; i < 2; ++i) {
            int idx = t + 256 * i;
            int tt = idx >> 7, c = idx & 127;
            float acc = tr1b[c];
            for (int h = 0; h < 128; ++h) {
                acc += s_temb[tt * 128 + h] * tr1w[(256 + h) * 128 + c];
                acc += thS[tt][h]           * tr1w[(384 + h) * 128 + c];
                acc += s_yb[h]              * tr1w[(128 + h) * 128 + c];
                acc += s_xb[h]              * tr1w[h * 128 + c];
            }
            d0[tt * 128 + c] = acc;
        }
    }
}

// ---------------------------------------------------------------------------
// Row precompute: hxe = x@E + e_b1 ; cb = x@P + d0[t]   (one fused GEMM)
// ---------------------------------------------------------------------------
__global__ __launch_bounds__(256) void rowpre_kernel(
    const float* __restrict__ x, const int* __restrict__ tin,
    const float* __restrict__ Wcat, const float* __restrict__ e_b1,
    const float* __restrict__ d0,
    float* __restrict__ hxeP, float* __restrict__ cbP)
{
    __shared__ float XsT[64][68];
    __shared__ int tS[64];
    __shared__ float eb1S[128];

    const int t = threadIdx.x;
    const int r0 = blockIdx.x * 64;
    if (t < 64) { int tv = tin[r0 + t]; tS[t] = tv > 0 ? tv : 0; }
    if (t < 128) eb1S[t] = e_b1[t];

    const int rg = t >> 4;       // 0..15
    const int cg = t & 15;       // 0..15
    const int R = rg << 2;

    float acc[4][16];
    #pragma unroll
    for (int rr = 0; rr < 4; ++rr)
        #pragma unroll
        for (int cc = 0; cc < 16; ++cc) acc[rr][cc] = 0.f;

    for (int kc = 0; kc < 4; ++kc) {
        __syncthreads();
        #pragma unroll
        for (int i = 0; i < 4; ++i) {
            int lin = t + 256 * i;           // 0..1023
            int rr = lin >> 4;               // 0..63
            int c4 = (lin & 15) << 2;        // 0..60
            float4 v = *(const float4*)&x[(size_t)(r0 + rr) * 256 + kc * 64 + c4];
            XsT[c4 + 0][rr] = v.x;
            XsT[c4 + 1][rr] = v.y;
            XsT[c4 + 2][rr] = v.z;
            XsT[c4 + 3][rr] = v.w;
        }
        __syncthreads();
        #pragma unroll 2
        for (int k = 0; k < 64; ++k) {
            float av[4];
            #pragma unroll
            for (int rr = 0; rr < 4; ++rr) av[rr] = XsT[k][R + rr];
            const float* wrow = &Wcat[(size_t)(kc * 64 + k) * 256 + cg];
            #pragma unroll
            for (int cc = 0; cc < 16; ++cc) {
                float bv = wrow[cc * 16];
                #pragma unroll
                for (int rr = 0; rr < 4; ++rr) acc[rr][cc] += av[rr] * bv;
            }
        }
    }
    #pragma unroll
    for (int cc = 0; cc < 8; ++cc) {
        int c = cg + (cc << 4);
        #pragma unroll
        for (int rr = 0; rr < 4; ++rr)
            hxeP[(size_t)(r0 + R + rr) * 128 + c] = acc[rr][cc] + eb1S[c];
    }
    #pragma unroll
    for (int cc = 8; cc < 16; ++cc) {
        int c = cg + ((cc - 8) << 4);
        #pragma unroll
        for (int rr = 0; rr < 4; ++rr)
            cbP[(size_t)(r0 + R + rr) * 128 + c] = acc[rr][cc] + d0[tS[R + rr] * 128 + c];
    }
}

// ---------------------------------------------------------------------------
// Iterate kernel (MFMA): 32 rows/block, 4 waves, 20 GD steps.
// Forward GEMMs (P1, P3) use exact 3-plane bf16 splits + 6-product MFMA
// (error ~1e-7 rel, f32-class -> ReLU masks match the f32 reference).
// Backward GEMMs (P4, P5) use 2-plane/3-product (smooth paths, 3e-5 ok).
// MFMA layouts (HW-verified per guide):
//   A: lane holds A[row=l&15][k=(l>>4)*8 + 0..7]
//   B: lane holds B[k=(l>>4)*8 + 0..7][col=l&15]   (from B^T, k-contiguous)
//   C/D: lane reg j = D[row=(l>>4)*4 + j][col=l&15]
// LDS ~73.0 KB -> 2 blocks/CU.
// ---------------------------------------------------------------------------
__global__ __launch_bounds__(256) void iterate_kernel(
    const float* __restrict__ hxeP, const float* __restrict__ cbP,
    const unsigned short* __restrict__ W1Tb0, const unsigned short* __restrict__ W1Tb1,
    const unsigned short* __restrict__ W1Tb2,
    const unsigned short* __restrict__ ew2Tb0, const unsigned short* __restrict__ ew2Tb1,
    const unsigned short* __restrict__ ew2Tb2,
    const unsigned short* __restrict__ ew2bh, const unsigned short* __restrict__ ew2bl,
    const unsigned short* __restrict__ Wdybh, const unsigned short* __restrict__ Wdybl,
    const float* __restrict__ e_w3, const float* __restrict__ tr2w,
    const float* __restrict__ tr2b, const float* __restrict__ e_b2,
    const int* __restrict__ tin, const int* __restrict__ stepsPtr,
    float* __restrict__ yout)
{
    __shared__ __align__(16) unsigned short H1a[32 * 136]; // h1 plane0, then dz1 hi
    __shared__ __align__(16) unsigned short H1b[32 * 136]; // h1 plane1, then dz1 lo
    __shared__ __align__(16) unsigned short H1c[32 * 136]; // h1 plane2
    __shared__ __align__(16) unsigned short DAa[32 * 136], DAb[32 * 136]; // da hi/lo
    __shared__ __align__(16) float U[32 * 140];     // 'a' f32, then dz2 hi/lo bf16
    __shared__ __align__(16) float yS[32 * 36];     // y master f32
    __shared__ __align__(16) float tr2wS[2 * 520];  // 2 bank-offset copies
    __shared__ float ew3S[512];
    __shared__ float eb2S[128];
    __shared__ float vSs[32];
    __shared__ int tcS[32];

    const int t = threadIdx.x;
    const int r0 = blockIdx.x * 32;
    const int w = t >> 6;        // wave 0..3
    const int l = t & 63;
    const int g = l >> 4;        // 0..3
    const int q = l & 15;        // 0..15

    if (t < 32) {
        int tv = tin[r0 + t];
        tcS[t] = tv > 0 ? tv : 0;
        vSs[t] = (tv >= 0) ? 1.f : 0.f;
    }
    if (t < 128) eb2S[t] = e_b2[t];
    for (int i = t; i < 512; i += 256) {
        float wv = tr2w[i];
        ew3S[i] = e_w3[i];
        tr2wS[i] = wv;
        tr2wS[520 + i] = wv;
    }
    for (int i = t; i < 32 * 36; i += 256) yS[i] = 0.f;

    // hxe/cb per-lane constants in registers for the whole kernel (32 f32/lane)
    float vhc[2][4][4];
    {
        const float* src = (w < 2) ? hxeP : cbP;
        const int cbase = (w < 2 ? w : (w - 2)) * 64;
        #pragma unroll
        for (int rt = 0; rt < 2; ++rt)
            #pragma unroll
            for (int ci = 0; ci < 4; ++ci)
                #pragma unroll
                for (int j = 0; j < 4; ++j)
                    vhc[rt][ci][j] =
                        src[(size_t)(r0 + rt * 16 + g * 4 + j) * 128 + cbase + ci * 16 + q];
    }

    // W1^T B-fragments are loop-invariant: hoist (12 s8b = 48 VGPR)
    s8b W1B0[4], W1B1[4], W1B2[4];
    #pragma unroll
    for (int ci = 0; ci < 4; ++ci) {
        const int col = (w * 4 + ci) * 16 + q;
        W1B0[ci] = *(const s8b*)&W1Tb0[col * 32 + g * 8];
        W1B1[ci] = *(const s8b*)&W1Tb1[col * 32 + g * 8];
        W1B2[ci] = *(const s8b*)&W1Tb2[col * 32 + g * 8];
    }

    const float tb0 = tr2b[0], tb1 = tr2b[1], tb2 = tr2b[2], tb3 = tr2b[3];
    const int nsteps = stepsPtr[0];
    const int row8 = t >> 3;     // P2 row
    const int p = t & 7;         // P2 h-slice

    __syncthreads();

    for (int step = 0; step < nsteps; ++step) {
        // ---------------- P1: z1 = y @ W1 (C 32x256); h1 -> H1, a -> U -------
        #pragma unroll
        for (int rt = 0; rt < 2; ++rt) {
            float4 ya = *(const float4*)&yS[(rt * 16 + q) * 36 + g * 8];
            float4 yb = *(const float4*)&yS[(rt * 16 + q) * 36 + g * 8 + 4];
            float yv[8] = {ya.x, ya.y, ya.z, ya.w, yb.x, yb.y, yb.z, yb.w};
            s8b Y0, Y1, Y2;
            split3x8(yv, Y0, Y1, Y2);
            #pragma unroll
            for (int ci = 0; ci < 4; ++ci) {
                const int col = (w * 4 + ci) * 16 + q;
                f32x4 acc = {0.f, 0.f, 0.f, 0.f};
                MFMA6(Y0, Y1, Y2, W1B0[ci], W1B1[ci], W1B2[ci], acc);
                if (w < 2) {
                    const int h = col;                      // 0..127
                    #pragma unroll
                    for (int j = 0; j < 4; ++j) {
                        const int rowL = rt * 16 + g * 4 + j;
                        float hv = acc[j] + vhc[rt][ci][j];
                        hv = hv > 0.f ? hv : 0.f;
                        const int idx = rowL * 136 + h;
                        unsigned u = __float_as_uint(hv);
                        H1a[idx] = (unsigned short)(u >> 16);
                        float r1 = hv - __uint_as_float(u & 0xffff0000u);
                        unsigned u1 = __float_as_uint(r1);
                        H1b[idx] = (unsigned short)(u1 >> 16);
                        float r2 = r1 - __uint_as_float(u1 & 0xffff0000u);
                        H1c[idx] = (unsigned short)(__float_as_uint(r2) >> 16);
                    }
                } else {
                    const int c = col - 128;                // 0..127
                    #pragma unroll
                    for (int j = 0; j < 4; ++j) {
                        const int rowL = rt * 16 + g * 4 + j;
                        U[rowL * 140 + c] = acc[j] + vhc[rt][ci][j];
                    }
                }
            }
        }
        __syncthreads();

        // ---------------- P2: pointwise CE (f32, unchanged math) -------------
        {
            float aval[16], sval[16];
            float lg0 = 0.f, lg1 = 0.f, lg2 = 0.f, lg3 = 0.f;
            const int h0 = p << 4;
            const float* ap = &U[row8 * 140 + h0];
            #pragma unroll
            for (int m = 0; m < 4; ++m) {
                float4 v4 = *(const float4*)&ap[m * 4];
                aval[m * 4 + 0] = v4.x; aval[m * 4 + 1] = v4.y;
                aval[m * 4 + 2] = v4.z; aval[m * 4 + 3] = v4.w;
            }
            const float* tw = &tr2wS[(p & 1) * 520];
            #pragma unroll
            for (int hh = 0; hh < 16; ++hh) {
                float a = aval[hh];
                float s = 1.f / (1.f + __expf(-a));
                sval[hh] = s;
                float u = a * s;
                float4 wv4 = *(const float4*)&tw[(h0 + hh) * 4];
                lg0 += u * wv4.x; lg1 += u * wv4.y;
                lg2 += u * wv4.z; lg3 += u * wv4.w;
            }
            #pragma unroll
            for (int m = 1; m < 8; m <<= 1) {
                lg0 += __shfl_xor(lg0, m);
                lg1 += __shfl_xor(lg1, m);
                lg2 += __shfl_xor(lg2, m);
                lg3 += __shfl_xor(lg3, m);
            }
            lg0 += tb0; lg1 += tb1; lg2 += tb2; lg3 += tb3;
            float mx = fmaxf(fmaxf(lg0, lg1), fmaxf(lg2, lg3));
            float e0 = __expf(lg0 - mx), e1 = __expf(lg1 - mx);
            float e2 = __expf(lg2 - mx), e3 = __expf(lg3 - mx);
            float inv = 1.f / (e0 + e1 + e2 + e3);
            int tcr = tcS[row8];
            float vd = vSs[row8];
            float dl0 = (e0 * inv - (tcr == 0 ? 1.f : 0.f)) * vd;
            float dl1 = (e1 * inv - (tcr == 1 ? 1.f : 0.f)) * vd;
            float dl2 = (e2 * inv - (tcr == 2 ? 1.f : 0.f)) * vd;
            float dl3 = (e3 * inv - (tcr == 3 ? 1.f : 0.f)) * vd;
            #pragma unroll
            for (int hh = 0; hh < 16; ++hh) {
                float a = aval[hh], s = sval[hh];
                float4 wv4 = *(const float4*)&tw[(h0 + hh) * 4];
                float du = dl0 * wv4.x + dl1 * wv4.y + dl2 * wv4.z + dl3 * wv4.w;
                aval[hh] = du * s * (1.f + a * (1.f - s));   // da
            }
            #pragma unroll
            for (int m = 0; m < 8; ++m) {
                float a0 = aval[2 * m], a1 = aval[2 * m + 1];
                *(unsigned*)&DAa[row8 * 136 + h0 + 2 * m] = hi2(a0, a1);
                *(unsigned*)&DAb[row8 * 136 + h0 + 2 * m] =
                    hi2(a0 - hipart(a0), a1 - hipart(a1));
            }
        }
        __syncthreads();

        // ---------------- P3: z2 = h1 @ e_w2 (hi-prec); dz2 -> U -------------
        {
            unsigned short* DZh = (unsigned short*)U;
            unsigned short* DZl = DZh + 32 * 136;
            #pragma unroll
            for (int rt = 0; rt < 2; ++rt) {
                s8b Aa[4], Ab[4], Ac[4];
                #pragma unroll
                for (int kc = 0; kc < 4; ++kc) {
                    const int off = (rt * 16 + q) * 136 + kc * 32 + g * 8;
                    Aa[kc] = *(const s8b*)&H1a[off];
                    Ab[kc] = *(const s8b*)&H1b[off];
                    Ac[kc] = *(const s8b*)&H1c[off];
                }
                #pragma unroll
                for (int c2 = 0; c2 < 2; ++c2) {
                    const int col = (w * 2 + c2) * 16 + q;   // 0..127
                    f32x4 acc = {0.f, 0.f, 0.f, 0.f};
                    #pragma unroll
                    for (int kc = 0; kc < 4; ++kc) {
                        const int wo = col * 128 + kc * 32 + g * 8;
                        s8b B0 = *(const s8b*)&ew2Tb0[wo];
                        s8b B1 = *(const s8b*)&ew2Tb1[wo];
                        s8b B2 = *(const s8b*)&ew2Tb2[wo];
                        MFMA6(Aa[kc], Ab[kc], Ac[kc], B0, B1, B2, acc);
                    }
                    const float ebv = eb2S[col];
                    #pragma unroll
                    for (int j = 0; j < 4; ++j) {
                        const int rowL = rt * 16 + g * 4 + j;
                        float gv = ew3S[col * 4 + tcS[rowL]];
                        float dz = (acc[j] + ebv) > 0.f ? gv : 0.f;
                        unsigned u = __float_as_uint(dz);
                        DZh[rowL * 136 + col] = (unsigned short)(u >> 16);
                        float hf = __uint_as_float(u & 0xffff0000u);
                        DZl[rowL * 136 + col] =
                            (unsigned short)(__float_as_uint(dz - hf) >> 16);
                    }
                }
            }
        }
        __syncthreads();

        // ---------------- P4: dh1 = dz2 @ e_w2^T ; dz1 -> H1a/H1b ------------
        {
            const unsigned short* DZh = (const unsigned short*)U;
            const unsigned short* DZl = DZh + 32 * 136;
            #pragma unroll
            for (int rt = 0; rt < 2; ++rt) {
                s8b Ah[4], Al[4];
                #pragma unroll
                for (int kc = 0; kc < 4; ++kc) {
                    const int off = (rt * 16 + q) * 136 + kc * 32 + g * 8;
                    Ah[kc] = *(const s8b*)&DZh[off];
                    Al[kc] = *(const s8b*)&DZl[off];
                }
                #pragma unroll
                for (int c2 = 0; c2 < 2; ++c2) {
                    const int col = (w * 2 + c2) * 16 + q;   // 0..127 (h index)
                    f32x4 acc = {0.f, 0.f, 0.f, 0.f};
                    #pragma unroll
                    for (int kc = 0; kc < 4; ++kc) {
                        const int wo = col * 128 + kc * 32 + g * 8;
                        s8b bh = *(const s8b*)&ew2bh[wo];
                        s8b bl = *(const s8b*)&ew2bl[wo];
                        acc = MFMA16(Ah[kc], bh, acc);
                        acc = MFMA16(Al[kc], bh, acc);
                        acc = MFMA16(Ah[kc], bl, acc);
                    }
                    #pragma unroll
                    for (int j = 0; j < 4; ++j) {
                        const int rowL = rt * 16 + g * 4 + j;
                        const int idx = rowL * 136 + col;
                        // mask from h1 plane0 bits (h1>=0: bits>0 iff h1>0)
                        float dz1 = ((short)H1a[idx] > 0) ? acc[j] : 0.f;
                        unsigned u = __float_as_uint(dz1);
                        H1a[idx] = (unsigned short)(u >> 16);
                        float hf = __uint_as_float(u & 0xffff0000u);
                        H1b[idx] = (unsigned short)(__float_as_uint(dz1 - hf) >> 16);
                    }
                }
            }
        }
        __syncthreads();

        // ---------------- P5: dy = [da|dz1] @ Wdy^T ; y update ---------------
        {
            const int rt = w >> 1, ctd = w & 1;
            const int d = ctd * 16 + q;
            f32x4 acc = {0.f, 0.f, 0.f, 0.f};
            #pragma unroll
            for (int kc = 0; kc < 8; ++kc) {
                const int off = (rt * 16 + q) * 136 + (kc & 3) * 32 + g * 8;
                s8b ah, al;
                if (kc < 4) { ah = *(const s8b*)&DAa[off]; al = *(const s8b*)&DAb[off]; }
                else        { ah = *(const s8b*)&H1a[off]; al = *(const s8b*)&H1b[off]; }
                s8b bh = *(const s8b*)&Wdybh[d * 256 + kc * 32 + g * 8];
                s8b bl = *(const s8b*)&Wdybl[d * 256 + kc * 32 + g * 8];
                acc = MFMA16(ah, bh, acc);
                acc = MFMA16(al, bh, acc);
                acc = MFMA16(ah, bl, acc);
            }
            #pragma unroll
            for (int j = 0; j < 4; ++j) {
                const int rowL = rt * 16 + g * 4 + j;
                float yv = yS[rowL * 36 + d];
                yv -= LRf * (acc[j] + 2.f * REGf * yv);
                yS[rowL * 36 + d] = yv;
            }
        }
        __syncthreads();
    }

    // ---------- write out ----------
    {
        const int row = t >> 3;
        const int d4 = (t & 7) * 4;
        float4 o = *(const float4*)&yS[row * 36 + d4];
        *(float4*)&yout[(size_t)(r0 + row) * 32 + d4] = o;
    }
}

// ---------------------------------------------------------------------------
extern "C" void kernel_launch(void* const* d_in, const int* in_sizes, int n_in,
                              void* d_out, int out_size, void* d_ws, size_t ws_size,
                              hipStream_t stream)
{
    const float* x      = (const float*)d_in[0];
    const int*   tin    = (const int*)d_in[1];
    const float* e_w1   = (const float*)d_in[2];
    const float* e_b1   = (const float*)d_in[3];
    const float* e_w2   = (const float*)d_in[4];
    const float* e_b2   = (const float*)d_in[5];
    const float* e_w3   = (const float*)d_in[6];
    const float* s_xw   = (const float*)d_in[8];
    const float* s_xb   = (const float*)d_in[9];
    const float* s_yw   = (const float*)d_in[10];
    const float* s_yb   = (const float*)d_in[11];
    const float* s_temb = (const float*)d_in[12];
    const float* s_t1w  = (const float*)d_in[13];
    const float* s_t1b  = (const float*)d_in[14];
    const float* s_t2w  = (const float*)d_in[15];
    const float* s_t2b  = (const float*)d_in[16];
    const float* tr1w   = (const float*)d_in[17];
    const float* tr1b   = (const float*)d_in[18];
    const float* tr2w   = (const float*)d_in[19];
    const float* tr2b   = (const float*)d_in[20];
    const int*   steps  = (const int*)d_in[21];

    const int B = in_sizes[0] / DXc;

    float* ws    = (float*)d_ws;
    float* hxeP  = ws;
    float* cbP   = hxeP + (size_t)B * 128;
    float* Wcat  = cbP  + (size_t)B * 128;
    float* W1    = Wcat + 256 * 256;
    float* d0    = W1   + 32 * 256;

    unsigned short* W1Tb0  = (unsigned short*)(d0 + 4 * 128);
    unsigned short* W1Tb1  = W1Tb0  + 256 * 32;
    unsigned short* W1Tb2  = W1Tb1  + 256 * 32;
    unsigned short* ew2Tb0 = W1Tb2  + 256 * 32;
    unsigned short* ew2Tb1 = ew2Tb0 + 128 * 128;
    unsigned short* ew2Tb2 = ew2Tb1 + 128 * 128;
    unsigned short* ew2bh  = ew2Tb2 + 128 * 128;
    unsigned short* ew2bl  = ew2bh  + 128 * 128;
    unsigned short* Wdybh  = ew2bl  + 128 * 128;
    unsigned short* Wdybl  = Wdybh  + 32 * 256;

    setup_kernel<<<68, 256, 0, stream>>>(e_w1, s_xw, s_yw, s_temb, s_t1w, s_t1b,
                                         s_t2w, s_t2b, tr1w, tr1b, s_xb, s_yb,
                                         e_w2, Wcat, W1, d0,
                                         W1Tb0, W1Tb1, W1Tb2,
                                         ew2Tb0, ew2Tb1, ew2Tb2,
                                         ew2bh, ew2bl, Wdybh, Wdybl);
    rowpre_kernel<<<B / 64, 256, 0, stream>>>(x, tin, Wcat, e_b1, d0, hxeP, cbP);
    iterate_kernel<<<B / 32, 256, 0, stream>>>(hxeP, cbP,
                                               W1Tb0, W1Tb1, W1Tb2,
                                               ew2Tb0, ew2Tb1, ew2Tb2,
                                               ew2bh, ew2bl, Wdybh, Wdybl,
                                               e_w3, tr2w, tr2b, e_b2, tin,
                                               steps, (float*)d_out);
}

// Round 3
// 3485.222 us; speedup vs baseline: 3.1724x; 1.0936x over previous
//
#include <hip/hip_runtime.h>
#include <hip/hip_bf16.h>

#define DXc 256
#define DYc 32
#define Kc 4
#define Hc 128
#define LRf 0.1f
#define REGf 0.01f
#define TSTEPS 1000

typedef __attribute__((ext_vector_type(8))) short s8b;    // 8 x bf16 (4 VGPRs)
typedef __attribute__((ext_vector_type(4))) float f32x4;  // MFMA accumulator

#define MFMA16(a, b, c) __builtin_amdgcn_mfma_f32_16x16x32_bf16((a), (b), (c), 0, 0, 0)

// 6-product "f32-exact" MFMA: A=a0+a1+a2, B=b0+b1+b2 (exact 3-way bf16 splits),
// keep terms down to 2^-18 order; dropped terms ~2^-24 relative.
#define MFMA6(A0, A1, A2, B0, B1, B2, acc)      \
    do {                                        \
        acc = MFMA16((A0), (B0), acc);          \
        acc = MFMA16((A0), (B1), acc);          \
        acc = MFMA16((A1), (B0), acc);          \
        acc = MFMA16((A0), (B2), acc);          \
        acc = MFMA16((A1), (B1), acc);          \
        acc = MFMA16((A2), (B0), acc);          \
    } while (0)

// ---- bf16 split helpers ----
__device__ __forceinline__ float hipart(float a) {
    return __uint_as_float(__float_as_uint(a) & 0xffff0000u);
}
__device__ __forceinline__ unsigned hi2(float a, float b) {
    return (__float_as_uint(a) >> 16) | (__float_as_uint(b) & 0xffff0000u);
}
// 2-way truncation split (residual ~2^-16 rel) — backward/smooth paths
__device__ __forceinline__ void wsplit(float x, unsigned short* __restrict__ h,
                                       unsigned short* __restrict__ l) {
    unsigned u = __float_as_uint(x);
    *h = (unsigned short)(u >> 16);
    float hf = __uint_as_float(u & 0xffff0000u);
    *l = (unsigned short)(__float_as_uint(x - hf) >> 16);
}
// 3-way truncation split — EXACT (8+8+8 >= 24 mantissa bits)
__device__ __forceinline__ void wsplit3(float x, unsigned short* __restrict__ p0,
                                        unsigned short* __restrict__ p1,
                                        unsigned short* __restrict__ p2) {
    unsigned u = __float_as_uint(x);
    *p0 = (unsigned short)(u >> 16);
    float r1 = x - __uint_as_float(u & 0xffff0000u);
    unsigned u1 = __float_as_uint(r1);
    *p1 = (unsigned short)(u1 >> 16);
    float r2 = r1 - __uint_as_float(u1 & 0xffff0000u);
    *p2 = (unsigned short)(__float_as_uint(r2) >> 16);
}
// exact 3-way split of 8 packed floats into 3 bf16x8 fragments
__device__ __forceinline__ void split3x8(const float* v, s8b& A0, s8b& A1, s8b& A2) {
    union { s8b s; unsigned u[4]; } P0, P1, P2;
    #pragma unroll
    for (int m = 0; m < 4; ++m) {
        float a = v[2 * m], b = v[2 * m + 1];
        unsigned ua = __float_as_uint(a), ub = __float_as_uint(b);
        P0.u[m] = (ua >> 16) | (ub & 0xffff0000u);
        float ra = a - __uint_as_float(ua & 0xffff0000u);
        float rb = b - __uint_as_float(ub & 0xffff0000u);
        unsigned ura = __float_as_uint(ra), urb = __float_as_uint(rb);
        P1.u[m] = (ura >> 16) | (urb & 0xffff0000u);
        float ra2 = ra - __uint_as_float(ura & 0xffff0000u);
        float rb2 = rb - __uint_as_float(urb & 0xffff0000u);
        P2.u[m] = (__float_as_uint(ra2) >> 16) | (__float_as_uint(rb2) & 0xffff0000u);
    }
    A0 = P0.s; A1 = P1.s; A2 = P2.s;
}
// 4-value splits, packed as uint2 (4 bf16) per plane
__device__ __forceinline__ void split3pack4(const float* v, uint2& Q0, uint2& Q1, uint2& Q2) {
    float r1[4], r2[4];
    #pragma unroll
    for (int i = 0; i < 4; ++i) {
        r1[i] = v[i] - hipart(v[i]);
        r2[i] = r1[i] - hipart(r1[i]);
    }
    Q0.x = hi2(v[0], v[1]);   Q0.y = hi2(v[2], v[3]);
    Q1.x = hi2(r1[0], r1[1]); Q1.y = hi2(r1[2], r1[3]);
    Q2.x = hi2(r2[0], r2[1]); Q2.y = hi2(r2[2], r2[3]);
}
__device__ __forceinline__ void split2pack4(const float* v, uint2& Q0, uint2& Q1) {
    Q0.x = hi2(v[0], v[1]); Q0.y = hi2(v[2], v[3]);
    float r0 = v[0] - hipart(v[0]), r1 = v[1] - hipart(v[1]);
    float r2 = v[2] - hipart(v[2]), r3 = v[3] - hipart(v[3]);
    Q1.x = hi2(r0, r1); Q1.y = hi2(r2, r3);
}

// ---------------------------------------------------------------------------
// Setup kernel (unchanged from round 2): derived weights into workspace.
// ---------------------------------------------------------------------------
__global__ __launch_bounds__(256) void setup_kernel(
    const float* __restrict__ e_w1, const float* __restrict__ s_xw,
    const float* __restrict__ s_yw, const float* __restrict__ s_temb,
    const float* __restrict__ s_t1w, const float* __restrict__ s_t1b,
    const float* __restrict__ s_t2w, const float* __restrict__ s_t2b,
    const float* __restrict__ tr1w, const float* __restrict__ tr1b,
    const float* __restrict__ s_xb, const float* __restrict__ s_yb,
    const float* __restrict__ e_w2,
    float* __restrict__ Wcat, float* __restrict__ W1, float* __restrict__ d0,
    unsigned short* __restrict__ W1Tb0, unsigned short* __restrict__ W1Tb1,
    unsigned short* __restrict__ W1Tb2,
    unsigned short* __restrict__ ew2Tb0, unsigned short* __restrict__ ew2Tb1,
    unsigned short* __restrict__ ew2Tb2,
    unsigned short* __restrict__ ew2bh, unsigned short* __restrict__ ew2bl,
    unsigned short* __restrict__ Wdybh, unsigned short* __restrict__ Wdybl)
{
    const int b = blockIdx.x;
    const int t = threadIdx.x;
    if (b < 64) {
        #pragma unroll
        for (int i = 0; i < 2; ++i) {
            int idx = t + 256 * i;              // 0..511
            int k = 4 * b + (idx >> 7);
            int c = idx & 127;
            float acc = 0.f;
            for (int h = 0; h < 128; ++h)
                acc += s_xw[k * 128 + h] * tr1w[h * 128 + c];
            Wcat[k * 256 + 128 + c] = acc;
            Wcat[k * 256 + c] = e_w1[k * 128 + c];
        }
    } else if (b == 64) {
        // M = s_yw @ A1   (W1 cols 128..255)
        #pragma unroll
        for (int i = 0; i < 16; ++i) {
            int idx = t + 256 * i;              // 0..4095
            int d = idx >> 7, c = idx & 127;
            float acc = 0.f;
            for (int h = 0; h < 128; ++h)
                acc += s_yw[d * 128 + h] * tr1w[(128 + h) * 128 + c];
            W1[d * 256 + 128 + c] = acc;
            wsplit3(acc, &W1Tb0[(128 + c) * 32 + d], &W1Tb1[(128 + c) * 32 + d],
                    &W1Tb2[(128 + c) * 32 + d]);
            wsplit(acc, &Wdybh[d * 256 + c], &Wdybl[d * 256 + c]);
        }
    } else if (b == 65) {
        // Wy = e_w1[256:288]  (W1 cols 0..127)
        #pragma unroll
        for (int i = 0; i < 16; ++i) {
            int idx = t + 256 * i;
            int d = idx >> 7, c = idx & 127;
            float v = e_w1[(DXc + d) * 128 + c];
            W1[d * 256 + c] = v;
            wsplit3(v, &W1Tb0[c * 32 + d], &W1Tb1[c * 32 + d], &W1Tb2[c * 32 + d]);
            wsplit(v, &Wdybh[d * 256 + 128 + c], &Wdybl[d * 256 + 128 + c]);
        }
    } else if (b == 66) {
        // e_w2 splits (both orientations)
        #pragma unroll
        for (int i = 0; i < 64; ++i) {
            int idx = t + 256 * i;
            int h = idx >> 7, c = idx & 127;
            float v = e_w2[h * 128 + c];
            wsplit3(v, &ew2Tb0[c * 128 + h], &ew2Tb1[c * 128 + h],
                    &ew2Tb2[c * 128 + h]);
            wsplit(v, &ew2bh[h * 128 + c], &ew2bl[h * 128 + c]);
        }
    } else {
        // b == 67: th table then d0 table
        __shared__ float thS[4][128];
        #pragma unroll
        for (int i = 0; i < 2; ++i) {
            int idx = t + 256 * i;              // 0..511
            int tt = idx >> 7, c = idx & 127;
            float tau = (float)tt / (float)TSTEPS;
            if (tau < 1e-6f) tau = 1e-6f;
            float acc = s_t2b[c];
            for (int h = 0; h < 128; ++h) {
                float aa = tau * s_t1w[h] + s_t1b[h];
                float s = 1.f / (1.f + expf(-aa));
                acc += aa * s * s_t2w[h * 128 + c];
            }
            thS[tt][c] = acc;
        }
        __syncthreads();
        #pragma unroll
        for (int i = 0; i < 2; ++i) {
            int idx = t + 256 * i;
            int tt = idx >> 7, c = idx & 127;
            float acc = tr1b[c];
            for (int h = 0; h < 128; ++h) {
                acc += s_temb[tt * 128 + h] * tr1w[(256 + h) * 128 + c];
                acc += thS[tt][h]           * tr1w[(384 + h) * 128 + c];
                acc += s_yb[h]              * tr1w[(128 + h) * 128 + c];
                acc += s_xb[h]              * tr1w[h * 128 + c];
            }
            d0[tt * 128 + c] = acc;
        }
    }
}

// ---------------------------------------------------------------------------
// Row precompute (unchanged): hxe = x@E + e_b1 ; cb = x@P + d0[t]
// ---------------------------------------------------------------------------
__global__ __launch_bounds__(256) void rowpre_kernel(
    const float* __restrict__ x, const int* __restrict__ tin,
    const float* __restrict__ Wcat, const float* __restrict__ e_b1,
    const float* __restrict__ d0,
    float* __restrict__ hxeP, float* __restrict__ cbP)
{
    __shared__ float XsT[64][68];
    __shared__ int tS[64];
    __shared__ float eb1S[128];

    const int t = threadIdx.x;
    const int r0 = blockIdx.x * 64;
    if (t < 64) { int tv = tin[r0 + t]; tS[t] = tv > 0 ? tv : 0; }
    if (t < 128) eb1S[t] = e_b1[t];

    const int rg = t >> 4;       // 0..15
    const int cg = t & 15;       // 0..15
    const int R = rg << 2;

    float acc[4][16];
    #pragma unroll
    for (int rr = 0; rr < 4; ++rr)
        #pragma unroll
        for (int cc = 0; cc < 16; ++cc) acc[rr][cc] = 0.f;

    for (int kc = 0; kc < 4; ++kc) {
        __syncthreads();
        #pragma unroll
        for (int i = 0; i < 4; ++i) {
            int lin = t + 256 * i;           // 0..1023
            int rr = lin >> 4;               // 0..63
            int c4 = (lin & 15) << 2;        // 0..60
            float4 v = *(const float4*)&x[(size_t)(r0 + rr) * 256 + kc * 64 + c4];
            XsT[c4 + 0][rr] = v.x;
            XsT[c4 + 1][rr] = v.y;
            XsT[c4 + 2][rr] = v.z;
            XsT[c4 + 3][rr] = v.w;
        }
        __syncthreads();
        #pragma unroll 2
        for (int k = 0; k < 64; ++k) {
            float av[4];
            #pragma unroll
            for (int rr = 0; rr < 4; ++rr) av[rr] = XsT[k][R + rr];
            const float* wrow = &Wcat[(size_t)(kc * 64 + k) * 256 + cg];
            #pragma unroll
            for (int cc = 0; cc < 16; ++cc) {
                float bv = wrow[cc * 16];
                #pragma unroll
                for (int rr = 0; rr < 4; ++rr) acc[rr][cc] += av[rr] * bv;
            }
        }
    }
    #pragma unroll
    for (int cc = 0; cc < 8; ++cc) {
        int c = cg + (cc << 4);
        #pragma unroll
        for (int rr = 0; rr < 4; ++rr)
            hxeP[(size_t)(r0 + R + rr) * 128 + c] = acc[rr][cc] + eb1S[c];
    }
    #pragma unroll
    for (int cc = 8; cc < 16; ++cc) {
        int c = cg + ((cc - 8) << 4);
        #pragma unroll
        for (int rr = 0; rr < 4; ++rr)
            cbP[(size_t)(r0 + R + rr) * 128 + c] = acc[rr][cc] + d0[tS[R + rr] * 128 + c];
    }
}

// ---------------------------------------------------------------------------
// Iterate kernel (transposed MFMA): 32 rows/block, 4 waves, 20 GD steps.
// Every GEMM computed TRANSPOSED (weights = A-operand, activations = B):
//   D-fragment lane holds 4 CONSECUTIVE output-feature values for one sample
//   -> epilogues are packed b64/b128 LDS ops, matching the row-major
//      k-contiguous layout every following B-fragment read needs.
// Forward (P1, P3): exact 3-plane + 6-product (f32-class; ReLU masks exact).
// Backward (P4, P5): 2-plane + 3-product (~2^-17, smooth paths).
// MFMA layouts (HW-verified): A[row=l&15][k=g*8+..]; B[k=g*8+..][col=l&15];
// D reg j = [row=g*4+j][col=l&15].
// ---------------------------------------------------------------------------
__global__ __launch_bounds__(256) void iterate_kernel(
    const float* __restrict__ hxeP, const float* __restrict__ cbP,
    const unsigned short* __restrict__ W1Tb0, const unsigned short* __restrict__ W1Tb1,
    const unsigned short* __restrict__ W1Tb2,
    const unsigned short* __restrict__ ew2Tb0, const unsigned short* __restrict__ ew2Tb1,
    const unsigned short* __restrict__ ew2Tb2,
    const unsigned short* __restrict__ ew2bh, const unsigned short* __restrict__ ew2bl,
    const unsigned short* __restrict__ Wdybh, const unsigned short* __restrict__ Wdybl,
    const float* __restrict__ e_w3, const float* __restrict__ tr2w,
    const float* __restrict__ tr2b, const float* __restrict__ e_b2,
    const int* __restrict__ tin, const int* __restrict__ stepsPtr,
    float* __restrict__ yout)
{
    __shared__ __align__(16) unsigned short H1a[32 * 136]; // h1 p0, then dz1 hi
    __shared__ __align__(16) unsigned short H1b[32 * 136]; // h1 p1, then dz1 lo
    __shared__ __align__(16) unsigned short H1c[32 * 136]; // h1 p2
    __shared__ __align__(16) unsigned short DAa[32 * 136], DAb[32 * 136]; // da hi/lo
    __shared__ __align__(16) float U[32 * 140];     // 'a' f32; then dz2 hi/lo bf16
    __shared__ __align__(16) float yS[32 * 36];     // y master f32 [sample][d]
    __shared__ __align__(16) float tr2wS[2 * 520];  // 2 bank-offset copies
    __shared__ float ew3S[512];
    __shared__ float eb2S[128];
    __shared__ float vSs[32];
    __shared__ int tcS[32];

    const int t = threadIdx.x;
    const int r0 = blockIdx.x * 32;
    const int w = t >> 6;        // wave 0..3
    const int l = t & 63;
    const int g = l >> 4;        // 0..3  (k-chunk / D row-quadrant)
    const int q = l & 15;        // 0..15 (A row / B col)

    if (t < 32) {
        int tv = tin[r0 + t];
        tcS[t] = tv > 0 ? tv : 0;
        vSs[t] = (tv >= 0) ? 1.f : 0.f;
    }
    if (t < 128) eb2S[t] = e_b2[t];
    for (int i = t; i < 512; i += 256) {
        float wv = tr2w[i];
        ew3S[i] = e_w3[i];
        tr2wS[i] = wv;
        tr2wS[520 + i] = wv;
    }
    for (int i = t; i < 32 * 36; i += 256) yS[i] = 0.f;

    // hxe/cb per-lane float4 constants (col-consecutive, matches D layout)
    float4 vhc4[4][2];
    {
        const float* src = (w < 2) ? hxeP : cbP;
        const int wb = (w < 2) ? w : (w - 2);
        #pragma unroll
        for (int ci = 0; ci < 4; ++ci)
            #pragma unroll
            for (int ct = 0; ct < 2; ++ct)
                vhc4[ci][ct] = *(const float4*)
                    &src[(size_t)(r0 + ct * 16 + q) * 128 + (wb * 4 + ci) * 16 + g * 4];
    }

    // W1^T A-fragments are loop-invariant: hoist (12 s8b = 48 VGPR)
    s8b W1A0[4], W1A1[4], W1A2[4];
    #pragma unroll
    for (int ci = 0; ci < 4; ++ci) {
        const int arow = (w * 4 + ci) * 16 + q;    // z1 col index 0..255
        W1A0[ci] = *(const s8b*)&W1Tb0[arow * 32 + g * 8];
        W1A1[ci] = *(const s8b*)&W1Tb1[arow * 32 + g * 8];
        W1A2[ci] = *(const s8b*)&W1Tb2[arow * 32 + g * 8];
    }

    const float tb0 = tr2b[0], tb1 = tr2b[1], tb2 = tr2b[2], tb3 = tr2b[3];
    const int nsteps = stepsPtr[0];
    const int row8 = t >> 3;     // P2 row
    const int p = t & 7;         // P2 h-slice

    __syncthreads();

    for (int step = 0; step < nsteps; ++step) {
        // ------- P1: z1^T = W1^T x y^T ; h1 -> H1 (packed), a -> U (b128) ----
        #pragma unroll
        for (int ct = 0; ct < 2; ++ct) {
            float4 ya = *(const float4*)&yS[(ct * 16 + q) * 36 + g * 8];
            float4 yb = *(const float4*)&yS[(ct * 16 + q) * 36 + g * 8 + 4];
            float yv[8] = {ya.x, ya.y, ya.z, ya.w, yb.x, yb.y, yb.z, yb.w};
            s8b Y0, Y1, Y2;
            split3x8(yv, Y0, Y1, Y2);
            #pragma unroll
            for (int ci = 0; ci < 4; ++ci) {
                f32x4 acc = {0.f, 0.f, 0.f, 0.f};
                MFMA6(W1A0[ci], W1A1[ci], W1A2[ci], Y0, Y1, Y2, acc);
                const float4 vb = vhc4[ci][ct];
                if (w < 2) {
                    float v[4];
                    v[0] = acc[0] + vb.x; v[1] = acc[1] + vb.y;
                    v[2] = acc[2] + vb.z; v[3] = acc[3] + vb.w;
                    #pragma unroll
                    for (int j = 0; j < 4; ++j) v[j] = v[j] > 0.f ? v[j] : 0.f;
                    uint2 Q0, Q1, Q2;
                    split3pack4(v, Q0, Q1, Q2);
                    const int off = (ct * 16 + q) * 136 + (w * 4 + ci) * 16 + g * 4;
                    *(uint2*)&H1a[off] = Q0;
                    *(uint2*)&H1b[off] = Q1;
                    *(uint2*)&H1c[off] = Q2;
                } else {
                    float4 o;
                    o.x = acc[0] + vb.x; o.y = acc[1] + vb.y;
                    o.z = acc[2] + vb.z; o.w = acc[3] + vb.w;
                    const int off = (ct * 16 + q) * 140 + ((w - 2) * 4 + ci) * 16 + g * 4;
                    *(float4*)&U[off] = o;
                }
            }
        }
        __syncthreads();

        // ---------------- P2: pointwise CE (f32, unchanged math) -------------
        {
            float aval[16], sval[16];
            float lg0 = 0.f, lg1 = 0.f, lg2 = 0.f, lg3 = 0.f;
            const int h0 = p << 4;
            const float* ap = &U[row8 * 140 + h0];
            #pragma unroll
            for (int m = 0; m < 4; ++m) {
                float4 v4 = *(const float4*)&ap[m * 4];
                aval[m * 4 + 0] = v4.x; aval[m * 4 + 1] = v4.y;
                aval[m * 4 + 2] = v4.z; aval[m * 4 + 3] = v4.w;
            }
            const float* tw = &tr2wS[(p & 1) * 520];
            #pragma unroll
            for (int hh = 0; hh < 16; ++hh) {
                float a = aval[hh];
                float s = 1.f / (1.f + __expf(-a));
                sval[hh] = s;
                float u = a * s;
                float4 wv4 = *(const float4*)&tw[(h0 + hh) * 4];
                lg0 += u * wv4.x; lg1 += u * wv4.y;
                lg2 += u * wv4.z; lg3 += u * wv4.w;
            }
            #pragma unroll
            for (int m = 1; m < 8; m <<= 1) {
                lg0 += __shfl_xor(lg0, m);
                lg1 += __shfl_xor(lg1, m);
                lg2 += __shfl_xor(lg2, m);
                lg3 += __shfl_xor(lg3, m);
            }
            lg0 += tb0; lg1 += tb1; lg2 += tb2; lg3 += tb3;
            float mx = fmaxf(fmaxf(lg0, lg1), fmaxf(lg2, lg3));
            float e0 = __expf(lg0 - mx), e1 = __expf(lg1 - mx);
            float e2 = __expf(lg2 - mx), e3 = __expf(lg3 - mx);
            float inv = 1.f / (e0 + e1 + e2 + e3);
            int tcr = tcS[row8];
            float vd = vSs[row8];
            float dl0 = (e0 * inv - (tcr == 0 ? 1.f : 0.f)) * vd;
            float dl1 = (e1 * inv - (tcr == 1 ? 1.f : 0.f)) * vd;
            float dl2 = (e2 * inv - (tcr == 2 ? 1.f : 0.f)) * vd;
            float dl3 = (e3 * inv - (tcr == 3 ? 1.f : 0.f)) * vd;
            #pragma unroll
            for (int hh = 0; hh < 16; ++hh) {
                float a = aval[hh], s = sval[hh];
                float4 wv4 = *(const float4*)&tw[(h0 + hh) * 4];
                float du = dl0 * wv4.x + dl1 * wv4.y + dl2 * wv4.z + dl3 * wv4.w;
                aval[hh] = du * s * (1.f + a * (1.f - s));   // da
            }
            #pragma unroll
            for (int m = 0; m < 8; ++m) {
                float a0 = aval[2 * m], a1 = aval[2 * m + 1];
                *(unsigned*)&DAa[row8 * 136 + h0 + 2 * m] = hi2(a0, a1);
                *(unsigned*)&DAb[row8 * 136 + h0 + 2 * m] =
                    hi2(a0 - hipart(a0), a1 - hipart(a1));
            }
        }
        __syncthreads();

        // ------- P3: z2^T = e_w2^T x h1^T (hi-prec); dz2 -> U region ---------
        {
            unsigned short* DZh = (unsigned short*)U;
            unsigned short* DZl = DZh + 32 * 136;
            #pragma unroll
            for (int ct = 0; ct < 2; ++ct) {
                s8b Ba[4], Bb[4], Bc[4];
                #pragma unroll
                for (int kc = 0; kc < 4; ++kc) {
                    const int off = (ct * 16 + q) * 136 + kc * 32 + g * 8;
                    Ba[kc] = *(const s8b*)&H1a[off];
                    Bb[kc] = *(const s8b*)&H1b[off];
                    Bc[kc] = *(const s8b*)&H1c[off];
                }
                #pragma unroll
                for (int c2 = 0; c2 < 2; ++c2) {
                    const int ctl = w * 2 + c2;
                    f32x4 acc = {0.f, 0.f, 0.f, 0.f};
                    #pragma unroll
                    for (int kc = 0; kc < 4; ++kc) {
                        const int wo = (ctl * 16 + q) * 128 + kc * 32 + g * 8;
                        s8b A0 = *(const s8b*)&ew2Tb0[wo];
                        s8b A1 = *(const s8b*)&ew2Tb1[wo];
                        s8b A2 = *(const s8b*)&ew2Tb2[wo];
                        MFMA6(A0, A1, A2, Ba[kc], Bb[kc], Bc[kc], acc);
                    }
                    const int cb = ctl * 16 + g * 4;
                    const int smp = ct * 16 + q;
                    const float4 eb = *(const float4*)&eb2S[cb];
                    const int tcr = tcS[smp];
                    float dz[4];
                    dz[0] = (acc[0] + eb.x) > 0.f ? ew3S[(cb + 0) * 4 + tcr] : 0.f;
                    dz[1] = (acc[1] + eb.y) > 0.f ? ew3S[(cb + 1) * 4 + tcr] : 0.f;
                    dz[2] = (acc[2] + eb.z) > 0.f ? ew3S[(cb + 2) * 4 + tcr] : 0.f;
                    dz[3] = (acc[3] + eb.w) > 0.f ? ew3S[(cb + 3) * 4 + tcr] : 0.f;
                    uint2 Q0, Q1;
                    split2pack4(dz, Q0, Q1);
                    const int off = smp * 136 + cb;
                    *(uint2*)&DZh[off] = Q0;
                    *(uint2*)&DZl[off] = Q1;
                }
            }
        }
        __syncthreads();

        // ------- P4: dh1^T = e_w2 x dz2^T ; dz1 -> H1a/H1b (packed) ----------
        {
            const unsigned short* DZh = (const unsigned short*)U;
            const unsigned short* DZl = DZh + 32 * 136;
            #pragma unroll
            for (int ct = 0; ct < 2; ++ct) {
                s8b Bh[4], Bl[4];
                #pragma unroll
                for (int kc = 0; kc < 4; ++kc) {
                    const int off = (ct * 16 + q) * 136 + kc * 32 + g * 8;
                    Bh[kc] = *(const s8b*)&DZh[off];
                    Bl[kc] = *(const s8b*)&DZl[off];
                }
                #pragma unroll
                for (int c2 = 0; c2 < 2; ++c2) {
                    const int htl = w * 2 + c2;
                    f32x4 acc = {0.f, 0.f, 0.f, 0.f};
                    #pragma unroll
                    for (int kc = 0; kc < 4; ++kc) {
                        const int wo = (htl * 16 + q) * 128 + kc * 32 + g * 8;
                        s8b Ah = *(const s8b*)&ew2bh[wo];
                        s8b Al = *(const s8b*)&ew2bl[wo];
                        acc = MFMA16(Ah, Bh[kc], acc);
                        acc = MFMA16(Al, Bh[kc], acc);
                        acc = MFMA16(Ah, Bl[kc], acc);
                    }
                    const int hb = htl * 16 + g * 4;
                    const int smp = ct * 16 + q;
                    const int off = smp * 136 + hb;
                    const uint2 mh = *(const uint2*)&H1a[off];  // h1 plane0 bits
                    float v[4];
                    v[0] = ((short)(mh.x & 0xffffu) > 0) ? acc[0] : 0.f;
                    v[1] = ((short)(mh.x >> 16)     > 0) ? acc[1] : 0.f;
                    v[2] = ((short)(mh.y & 0xffffu) > 0) ? acc[2] : 0.f;
                    v[3] = ((short)(mh.y >> 16)     > 0) ? acc[3] : 0.f;
                    uint2 Q0, Q1;
                    split2pack4(v, Q0, Q1);
                    *(uint2*)&H1a[off] = Q0;
                    *(uint2*)&H1b[off] = Q1;
                }
            }
        }
        __syncthreads();

        // ------- P5: dy^T = Wdy x [da|dz1]^T ; y update (b128 RMW) -----------
        {
            const int dt = w >> 1, st = w & 1;
            f32x4 acc = {0.f, 0.f, 0.f, 0.f};
            #pragma unroll
            for (int kc = 0; kc < 8; ++kc) {
                const int boff = (st * 16 + q) * 136 + (kc & 3) * 32 + g * 8;
                s8b bh, bl;
                if (kc < 4) { bh = *(const s8b*)&DAa[boff]; bl = *(const s8b*)&DAb[boff]; }
                else        { bh = *(const s8b*)&H1a[boff]; bl = *(const s8b*)&H1b[boff]; }
                const int aoff = (dt * 16 + q) * 256 + kc * 32 + g * 8;
                s8b ah = *(const s8b*)&Wdybh[aoff];
                s8b al = *(const s8b*)&Wdybl[aoff];
                acc = MFMA16(ah, bh, acc);
                acc = MFMA16(al, bh, acc);
                acc = MFMA16(ah, bl, acc);
            }
            const int smp = st * 16 + q;
            const int db = dt * 16 + g * 4;
            float4 yv4 = *(const float4*)&yS[smp * 36 + db];
            yv4.x -= LRf * (acc[0] + 2.f * REGf * yv4.x);
            yv4.y -= LRf * (acc[1] + 2.f * REGf * yv4.y);
            yv4.z -= LRf * (acc[2] + 2.f * REGf * yv4.z);
            yv4.w -= LRf * (acc[3] + 2.f * REGf * yv4.w);
            *(float4*)&yS[smp * 36 + db] = yv4;
        }
        __syncthreads();
    }

    // ---------- write out ----------
    {
        const int row = t >> 3;
        const int d4 = (t & 7) * 4;
        float4 o = *(const float4*)&yS[row * 36 + d4];
        *(float4*)&yout[(size_t)(r0 + row) * 32 + d4] = o;
    }
}

// ---------------------------------------------------------------------------
extern "C" void kernel_launch(void* const* d_in, const int* in_sizes, int n_in,
                              void* d_out, int out_size, void* d_ws, size_t ws_size,
                              hipStream_t stream)
{
    const float* x      = (const float*)d_in[0];
    const int*   tin    = (const int*)d_in[1];
    const float* e_w1   = (const float*)d_in[2];
    const float* e_b1   = (const float*)d_in[3];
    const float* e_w2   = (const float*)d_in[4];
    const float* e_b2   = (const float*)d_in[5];
    const float* e_w3   = (const float*)d_in[6];
    const float* s_xw   = (const float*)d_in[8];
    const float* s_xb   = (const float*)d_in[9];
    const float* s_yw   = (const float*)d_in[10];
    const float* s_yb   = (const float*)d_in[11];
    const float* s_temb = (const float*)d_in[12];
    const float* s_t1w  = (const float*)d_in[13];
    const float* s_t1b  = (const float*)d_in[14];
    const float* s_t2w  = (const float*)d_in[15];
    const float* s_t2b  = (const float*)d_in[16];
    const float* tr1w   = (const float*)d_in[17];
    const float* tr1b   = (const float*)d_in[18];
    const float* tr2w   = (const float*)d_in[19];
    const float* tr2b   = (const float*)d_in[20];
    const int*   steps  = (const int*)d_in[21];

    const int B = in_sizes[0] / DXc;

    float* ws    = (float*)d_ws;
    float* hxeP  = ws;
    float* cbP   = hxeP + (size_t)B * 128;
    float* Wcat  = cbP  + (size_t)B * 128;
    float* W1    = Wcat + 256 * 256;
    float* d0    = W1   + 32 * 256;

    unsigned short* W1Tb0  = (unsigned short*)(d0 + 4 * 128);
    unsigned short* W1Tb1  = W1Tb0  + 256 * 32;
    unsigned short* W1Tb2  = W1Tb1  + 256 * 32;
    unsigned short* ew2Tb0 = W1Tb2  + 256 * 32;
    unsigned short* ew2Tb1 = ew2Tb0 + 128 * 128;
    unsigned short* ew2Tb2 = ew2Tb1 + 128 * 128;
    unsigned short* ew2bh  = ew2Tb2 + 128 * 128;
    unsigned short* ew2bl  = ew2bh  + 128 * 128;
    unsigned short* Wdybh  = ew2bl  + 128 * 128;
    unsigned short* Wdybl  = Wdybh  + 32 * 256;

    setup_kernel<<<68, 256, 0, stream>>>(e_w1, s_xw, s_yw, s_temb, s_t1w, s_t1b,
                                         s_t2w, s_t2b, tr1w, tr1b, s_xb, s_yb,
                                         e_w2, Wcat, W1, d0,
                                         W1Tb0, W1Tb1, W1Tb2,
                                         ew2Tb0, ew2Tb1, ew2Tb2,
                                         ew2bh, ew2bl, Wdybh, Wdybl);
    rowpre_kernel<<<B / 64, 256, 0, stream>>>(x, tin, Wcat, e_b1, d0, hxeP, cbP);
    iterate_kernel<<<B / 32, 256, 0, stream>>>(hxeP, cbP,
                                               W1Tb0, W1Tb1, W1Tb2,
                                               ew2Tb0, ew2Tb1, ew2Tb2,
                                               ew2bh, ew2bl, Wdybh, Wdybl,
                                               e_w3, tr2w, tr2b, e_b2, tin,
                                               steps, (float*)d_out);
}